// Round 11
// baseline (3236.708 us; speedup 1.0000x reference)
//
#include <hip/hip_runtime.h>
#include <cstdint>
#include <cstddef>

// ============================================================================
// ConditionalRBM sampler — bit-exact resimulation of the JAX reference.
//
// Round-11 pivot: three rounds (R8 unroll, R9 named regs, R10 SGB) proved
// hipcc will not keep in-loop GLOBAL loads in flight (VGPR stuck at 44-48,
// one L2 round-trip per k). Meanwhile R4 showed LDS reads DO run at their
// throughput bound. Therefore: zero global loads in the inner loop, and
// kill the state-operand LDS stream entirely by BIT-PACKING the 0/1 state:
//  - thread's 4 rows x 64k chunk-masks = 8 B in registers (named mA/mB,
//    prefetched a chunk ahead; static indices only)
//  - multiplicand s = (float)((word>>kk)&1) = exactly 1.0f / +0.0f ==
//    the stored float values -> fma chain operands BIT-IDENTICAL
//  - W is the only streamed operand: [64k][64c] LDS chunks, double-buffered;
//    per k: 1 ds_read_b128 (12cy LDS) + 4 bfe + 4 cvt + 16 fma (48cy VALU)
//  - per-CU model: LDS 10.2us, VALU 10.2us per phase (balanced, ~2x R4)
//  - packed-state output: k_init via __ballot (wave = 64 cols of one row);
//    k_phase via LDS nibble pack (4 KiB scratch)
// Block 64x64, 4x4 tile, grid 512 = 2 blocks/CU = 2 waves/SIMD; 36 KiB LDS.
// Accumulation order per output unchanged: ascending-k single-acc fma chain.
//
// ASSUMPTION STACK (verified bit-exact in earlier rounds):
//  A1: jax_threefry_partitionable = True:
//      split(key,n)[i] = TF(key,(0,i)); bits32[j] = TF0(key,(0,j)) ^ TF1(key,(0,j))
//  A2: logistic(x) = 1/(1+exp(-x)), IEEE fdiv
//  A3: exp = XLA-CPU vectorized Cephes/Eigen pexp
//  A4: dot = ascending-k single-accumulator fma chain (exact 0/1 products)
//  A5: x = (dot + udot) + bias association
//  Output dtype: int32 0/1 (harness reads d_out as int32).
// ============================================================================

#pragma clang fp contract(off)

#define BATCH 8192
#define NU 64
#define NF 256   // num_v == num_h == 256
#define BM 64    // rows per block in k_phase
#define BN 64    // cols per block in k_phase
#define BK 64    // k per staged W chunk
#define RTI 16   // rows per block in k_init / k_udot
#define THERM 24
#define NSAMP 8

// ---------------- Threefry-2x32 (JAX rotation/injection schedule) ----------
__host__ __device__ __forceinline__ void tf2x32(uint32_t k0, uint32_t k1,
                                                uint32_t x0, uint32_t x1,
                                                uint32_t* o0, uint32_t* o1) {
  uint32_t ks2 = k0 ^ k1 ^ 0x1BD11BDAu;
  x0 += k0; x1 += k1;
#define TFR(r) { x0 += x1; x1 = (x1 << (r)) | (x1 >> (32 - (r))); x1 ^= x0; }
  TFR(13) TFR(15) TFR(26) TFR(6)
  x0 += k1;  x1 += ks2 + 1u;
  TFR(17) TFR(29) TFR(16) TFR(24)
  x0 += ks2; x1 += k0 + 2u;
  TFR(13) TFR(15) TFR(26) TFR(6)
  x0 += k0;  x1 += k1 + 3u;
  TFR(17) TFR(29) TFR(16) TFR(24)
  x0 += k1;  x1 += ks2 + 4u;
  TFR(13) TFR(15) TFR(26) TFR(6)
  x0 += ks2; x1 += k0 + 5u;
#undef TFR
  *o0 = x0; *o1 = x1;
}

// ---------------- XLA-CPU expf (Cephes/Eigen polynomial) -------------------
__device__ __forceinline__ float xla_expf(float x) {
  float xc = fminf(x, 88.3762626647950f);
  xc = fmaxf(xc, -88.3762626647949f);
  float fx = floorf(__builtin_fmaf(xc, 1.44269504088896341f, 0.5f));
  float tmp = 0.693359375f * fx;          // separate rounding (contract off)
  float z = -2.12194440e-4f * fx;
  float r = xc - tmp;
  r = r - z;
  z = r * r;
  float y = __builtin_fmaf(r, 1.9875691500e-4f, 1.3981999507e-3f);
  y = __builtin_fmaf(y, r, 8.3334519073e-3f);
  y = __builtin_fmaf(y, r, 4.1665795894e-2f);
  y = __builtin_fmaf(y, r, 1.6666665459e-1f);
  y = __builtin_fmaf(y, r, 5.0000001201e-1f);
  y = __builtin_fmaf(y, z, r);
  y = y + 1.0f;
  int n = (int)fx;
  float p2 = __int_as_float((n + 127) << 23);
  float res = y * p2;
  return fmaxf(res, x);                   // Eigen pexp: pmax(res, original x)
}

__device__ __forceinline__ float sigmoid_ref(float x) {
  float e = xla_expf(-x);                 // negate exact
  return 1.0f / (1.0f + e);               // IEEE fdiv (no fast-math)
}

// bern: partitionable threefry bits -> uniform [0,1) -> (u < p)
__device__ __forceinline__ float bern_sample(uint32_t key0, uint32_t key1,
                                             uint32_t idx, float p) {
  uint32_t b0, b1;
  tf2x32(key0, key1, 0u, idx, &b0, &b1);  // counter = (hi=0, lo=flat_idx)
  uint32_t bits = b0 ^ b1;                // 32-bit path XORs both words
  float u = __uint_as_float((bits >> 9) | 0x3f800000u) - 1.0f;
  return (u < p) ? 1.0f : 0.0f;
}

// ---------------- kernels ---------------------------------------------------
__global__ void k_transpose(const float* __restrict__ Whv,
                            float* __restrict__ WhvT) {
  int j = threadIdx.x;  // hidden
  int k = blockIdx.x;   // visible
  WhvT[k * NF + j] = Whv[j * NF + k];
}

// out[row][j] = sum_k u[row][k] * W[j][k], ascending k (exact products).
__global__ __launch_bounds__(256, 2) void k_udot(const float* __restrict__ U,
                                                 const float* __restrict__ W,
                                                 float* __restrict__ out) {
  __shared__ __align__(16) float Ulds[NU * RTI];  // [k][i], 4 KiB
  const int j = threadIdx.x;
  const int i0 = blockIdx.x * RTI;
  const int si = j & 15;
  const int sg = j >> 4;
  {
    float4 u4 = *(const float4*)(U + (size_t)(i0 + si) * NU + sg * 4);
    Ulds[(sg * 4 + 0) * RTI + si] = u4.x;
    Ulds[(sg * 4 + 1) * RTI + si] = u4.y;
    Ulds[(sg * 4 + 2) * RTI + si] = u4.z;
    Ulds[(sg * 4 + 3) * RTI + si] = u4.w;
  }
  float wreg[NU];
  const float4* wr4 = (const float4*)(W + (size_t)j * NU);
#pragma unroll
  for (int r = 0; r < NU / 4; ++r) {
    float4 t = wr4[r];
    wreg[4 * r + 0] = t.x; wreg[4 * r + 1] = t.y;
    wreg[4 * r + 2] = t.z; wreg[4 * r + 3] = t.w;
  }
  __syncthreads();
  float acc[RTI];
#pragma unroll
  for (int i = 0; i < RTI; ++i) acc[i] = 0.0f;
#pragma unroll
  for (int kk = 0; kk < NU; ++kk) {
    const float w = wreg[kk];
    const float4 s0 = *(const float4*)(&Ulds[kk * RTI + 0]);
    const float4 s1 = *(const float4*)(&Ulds[kk * RTI + 4]);
    const float4 s2 = *(const float4*)(&Ulds[kk * RTI + 8]);
    const float4 s3 = *(const float4*)(&Ulds[kk * RTI + 12]);
    acc[0]  = __builtin_fmaf(s0.x, w, acc[0]);
    acc[1]  = __builtin_fmaf(s0.y, w, acc[1]);
    acc[2]  = __builtin_fmaf(s0.z, w, acc[2]);
    acc[3]  = __builtin_fmaf(s0.w, w, acc[3]);
    acc[4]  = __builtin_fmaf(s1.x, w, acc[4]);
    acc[5]  = __builtin_fmaf(s1.y, w, acc[5]);
    acc[6]  = __builtin_fmaf(s1.z, w, acc[6]);
    acc[7]  = __builtin_fmaf(s1.w, w, acc[7]);
    acc[8]  = __builtin_fmaf(s2.x, w, acc[8]);
    acc[9]  = __builtin_fmaf(s2.y, w, acc[9]);
    acc[10] = __builtin_fmaf(s2.z, w, acc[10]);
    acc[11] = __builtin_fmaf(s2.w, w, acc[11]);
    acc[12] = __builtin_fmaf(s3.x, w, acc[12]);
    acc[13] = __builtin_fmaf(s3.y, w, acc[13]);
    acc[14] = __builtin_fmaf(s3.z, w, acc[14]);
    acc[15] = __builtin_fmaf(s3.w, w, acc[15]);
  }
#pragma unroll
  for (int i = 0; i < RTI; ++i)
    out[(size_t)(i0 + i) * NF + j] = acc[i];   // row-major (coalesced)
}

// v0 = bern(ks[0], sigmoid(uv + bv)); emits PACKED state bits via ballot.
// Wave w covers cols 64w..64w+63 of each of the block's 16 rows -> one
// __ballot per row = exactly that row's two 32-bit words.
__global__ __launch_bounds__(256) void k_init(const float* __restrict__ uv,
                                              const float* __restrict__ bv,
                                              uint32_t* __restrict__ Vb,
                                              uint32_t key0, uint32_t key1) {
  const int j = threadIdx.x;
  const int i0 = blockIdx.x * RTI;
  const int wv = j >> 6, lane = j & 63;
  const float b = bv[j];
#pragma unroll
  for (int i = 0; i < RTI; ++i) {
    const int row = i0 + i;
    const uint32_t idx = (uint32_t)(row * NF + j);
    const float p = sigmoid_ref(uv[idx] + b);
    const float v = bern_sample(key0, key1, idx, p);
    unsigned long long m = __ballot(v != 0.0f);   // bit l = col 64*wv + l
    if (lane == 0)
      *(uint2*)(Vb + (size_t)row * 8 + 2 * wv) =
          make_uint2((uint32_t)m, (uint32_t)(m >> 32));
  }
}

// One Gibbs half-step: Ob = bern(key, sigmoid((S @ W) + C + bias)), packed.
// Sb: prev state bits [8192][8 words]; W: [256 k][256 j] k-major;
// C: u-dot [8192][256]; Ob: next-state bits; smp: optional int32 samples.
// Block 64x64, thread 4x4. W chunks [64][64] double-buffered in LDS;
// inner loop: 1 ds_read_b128 (W) + 4 bfe + 4 cvt + 16 fma per k — no
// global loads, no barriers inside a chunk. Masks prefetched a chunk ahead.
__global__ __launch_bounds__(256, 2) void k_phase(
    const uint32_t* __restrict__ Sb, const float* __restrict__ W,
    const float* __restrict__ C, const float* __restrict__ bias,
    uint32_t* __restrict__ Ob, int* __restrict__ smp,
    uint32_t key0, uint32_t key1) {
  __shared__ __align__(16) float Wlds[2 * BK * BN];  // 32 KiB
  __shared__ uint32_t Nib[BM * 16];                  // 4 KiB nibble scratch
  const int t  = threadIdx.x;
  const int i0 = (blockIdx.x & 127) * BM;   // 128 row-blocks (consecutive ids
  const int c0 = (blockIdx.x >> 7) * BN;    //   share the same W col-slice)
  const int rg = t >> 4, cg = t & 15;
  const int jc = c0 + cg * 4;               // thread's 4 cols
  const int r0 = i0 + rg * 4;               // thread's 4 rows

  float4 wst[4];
  uint2 mA[4], mB[4];
  float acc[16];
#pragma unroll
  for (int q = 0; q < 16; ++q) acc[q] = 0.0f;

#define LDGW(kc)                                                            \
  _Pragma("unroll") for (int q = 0; q < 4; ++q) {                           \
    const int f = q * 256 + t, k = f >> 4, c4 = (f & 15) * 4;               \
    wst[q] = *(const float4*)(W + (size_t)((kc) + k) * NF + c0 + c4);       \
  }
#define STW(boff)                                                           \
  _Pragma("unroll") for (int q = 0; q < 4; ++q) {                           \
    const int f = q * 256 + t, k = f >> 4, c4 = (f & 15) * 4;               \
    *(float4*)(&Wlds[(boff) + k * BN + c4]) = wst[q];                       \
  }
#define LDM(m, c)                                                           \
  _Pragma("unroll") for (int ri = 0; ri < 4; ++ri)                          \
    m[ri] = *(const uint2*)(Sb + (size_t)(r0 + ri) * 8 + 2 * (c));
#define CHUNK(boff, m)                                                      \
  _Pragma("unroll") for (int kk = 0; kk < BK; ++kk) {                       \
    const float4 w = *(const float4*)(&Wlds[(boff) + kk * BN + cg * 4]);    \
    _Pragma("unroll") for (int ri = 0; ri < 4; ++ri) {                      \
      const uint32_t wd = (kk < 32) ? m[ri].x : m[ri].y; /* static sel */   \
      const float s = (float)((wd >> (kk & 31)) & 1u);   /* 1.0f / +0.0f */ \
      acc[ri * 4 + 0] = __builtin_fmaf(s, w.x, acc[ri * 4 + 0]);            \
      acc[ri * 4 + 1] = __builtin_fmaf(s, w.y, acc[ri * 4 + 1]);            \
      acc[ri * 4 + 2] = __builtin_fmaf(s, w.z, acc[ri * 4 + 2]);            \
      acc[ri * 4 + 3] = __builtin_fmaf(s, w.w, acc[ri * 4 + 3]);            \
    }                                                                       \
  }

  // prologue: chunk 0 into buf0; masks for chunk 0
  LDGW(0) LDM(mA, 0)
  STW(0)
  __syncthreads();

  for (int cc = 0; cc < 2; ++cc) {          // chunks 2cc and 2cc+1
    LDGW((2 * cc + 1) * BK) LDM(mB, 2 * cc + 1)   // prefetch next chunk
    __builtin_amdgcn_sched_barrier(0);            // keep loads issued early
    CHUNK(0, mA)                                  // compute chunk 2cc (buf0)
    __builtin_amdgcn_sched_barrier(0);            // keep STW drain after
    STW(BK * BN)
    __syncthreads();
    if (cc == 0) {
      LDGW(2 * BK) LDM(mA, 2)                     // prefetch chunk 2
      __builtin_amdgcn_sched_barrier(0);
    }
    CHUNK(BK * BN, mB)                            // compute chunk 2cc+1 (buf1)
    __builtin_amdgcn_sched_barrier(0);
    if (cc == 0) {
      STW(0)
      __syncthreads();
    }
  }
#undef LDGW
#undef STW
#undef LDM
#undef CHUNK

  // epilogue: x = (dot + udot) + bias ; p = sigmoid ; bern
  const float4 b4 = *(const float4*)(bias + jc);
  float vals[16];
#pragma unroll
  for (int ri = 0; ri < 4; ++ri) {
    const int row = r0 + ri;
    const float4 c4 = *(const float4*)(C + (size_t)row * NF + jc);
    const uint32_t idx0 = (uint32_t)(row * NF + jc);
    vals[ri * 4 + 0] = bern_sample(key0, key1, idx0 + 0,
        sigmoid_ref((acc[ri * 4 + 0] + c4.x) + b4.x));
    vals[ri * 4 + 1] = bern_sample(key0, key1, idx0 + 1,
        sigmoid_ref((acc[ri * 4 + 1] + c4.y) + b4.y));
    vals[ri * 4 + 2] = bern_sample(key0, key1, idx0 + 2,
        sigmoid_ref((acc[ri * 4 + 2] + c4.z) + b4.z));
    vals[ri * 4 + 3] = bern_sample(key0, key1, idx0 + 3,
        sigmoid_ref((acc[ri * 4 + 3] + c4.w) + b4.w));
  }

  // int32 sample output (row-major)
  if (smp) {
#pragma unroll
    for (int ri = 0; ri < 4; ++ri) {
      const int row = r0 + ri;
      int4 o;
      o.x = (vals[ri * 4 + 0] != 0.0f) ? 1 : 0;
      o.y = (vals[ri * 4 + 1] != 0.0f) ? 1 : 0;
      o.z = (vals[ri * 4 + 2] != 0.0f) ? 1 : 0;
      o.w = (vals[ri * 4 + 3] != 0.0f) ? 1 : 0;
      *(int4*)(smp + (size_t)row * NF + jc) = o;
    }
  }

  // packed next-state: nibble per (row, cg) -> LDS -> word assembly
#pragma unroll
  for (int ri = 0; ri < 4; ++ri) {
    uint32_t nb = (vals[ri * 4 + 0] != 0.0f ? 1u : 0u) |
                  (vals[ri * 4 + 1] != 0.0f ? 2u : 0u) |
                  (vals[ri * 4 + 2] != 0.0f ? 4u : 0u) |
                  (vals[ri * 4 + 3] != 0.0f ? 8u : 0u);
    Nib[(rg * 4 + ri) * 16 + cg] = nb;
  }
  __syncthreads();
  if (t < 128) {                       // 2 words per row: 64 rows x 2
    const int row = t >> 1, half = t & 1;
    const uint32_t* nb = &Nib[row * 16 + half * 8];
    uint32_t wrd = nb[0] | (nb[1] << 4) | (nb[2] << 8) | (nb[3] << 12) |
                   (nb[4] << 16) | (nb[5] << 20) | (nb[6] << 24) | (nb[7] << 28);
    Ob[(size_t)(i0 + row) * 8 + (c0 >> 5) + half] = wrd;
  }
}

// ---------------- launch ----------------------------------------------------
extern "C" void kernel_launch(void* const* d_in, const int* in_sizes, int n_in,
                              void* d_out, int out_size, void* d_ws, size_t ws_size,
                              hipStream_t stream) {
  const float* u_state = (const float*)d_in[0];  // [8192][64] 0/1 floats
  const float* Wvu     = (const float*)d_in[1];  // [256][64]
  const float* Whu     = (const float*)d_in[2];  // [256][64]
  const float* Whv     = (const float*)d_in[3];  // [256][256]
  const float* bv      = (const float*)d_in[4];  // [256]
  const float* bh      = (const float*)d_in[5];  // [256]
  int* out = (int*)d_out;                        // [8][8192][256] as int32 0/1

  // workspace layout: WhvT 256KB, uh/uv 8MB each, Vb/Hb 256KB each (~17.3MB)
  float* ws   = (float*)d_ws;
  float* WhvT = ws;                          // 65536 f
  float* uh   = WhvT + NF * NF;              // [8192][256]
  float* uv   = uh + (size_t)BATCH * NF;
  uint32_t* Vb = (uint32_t*)(uv + (size_t)BATCH * NF);  // [8192][8]
  uint32_t* Hb = Vb + (size_t)BATCH * 8;                // [8192][8]

  // ---- host-side key schedule (pure CPU, deterministic) ----
  uint32_t s0[THERM + NSAMP + 1], s1[THERM + NSAMP + 1];
  for (uint32_t i = 0; i < THERM + NSAMP + 1; ++i)
    tf2x32(0u, 1u, 0u, i, &s0[i], &s1[i]);

  k_transpose<<<NF, NF, 0, stream>>>(Whv, WhvT);
  k_udot<<<BATCH / RTI, NF, 0, stream>>>(u_state, Whu, uh);   // u @ Whu.T
  k_udot<<<BATCH / RTI, NF, 0, stream>>>(u_state, Wvu, uv);   // u @ Wvu.T
  k_init<<<BATCH / RTI, NF, 0, stream>>>(uv, bv, Vb, s0[0], s1[0]);

  const int phase_blocks = (BATCH / BM) * (NF / BN);   // 128 * 4 = 512
  for (int t = 0; t < THERM + NSAMP; ++t) {
    uint32_t kh0, kh1, kv0, kv1;
    tf2x32(s0[1 + t], s1[1 + t], 0u, 0u, &kh0, &kh1);
    tf2x32(s0[1 + t], s1[1 + t], 0u, 1u, &kv0, &kv1);
    int* smp = (t >= THERM) ? out + (size_t)(t - THERM) * BATCH * NF : (int*)nullptr;
    // h = bern(k1, sigmoid(v @ Whv.T + uh + bh))
    k_phase<<<phase_blocks, NF, 0, stream>>>(Vb, WhvT, uh, bh, Hb, (int*)nullptr, kh0, kh1);
    // v = bern(k2, sigmoid(h @ Whv + uv + bv)) ; emit sample when t>=THERM
    k_phase<<<phase_blocks, NF, 0, stream>>>(Hb, Whv, uv, bv, Vb, smp, kv0, kv1);
  }
  (void)in_sizes; (void)n_in; (void)out_size; (void)ws_size;
}

// Round 12
// 1634.621 us; speedup vs baseline: 1.9801x; 1.9801x over previous
//
#include <hip/hip_runtime.h>
#include <cstdint>
#include <cstddef>

// ============================================================================
// ConditionalRBM sampler — bit-exact resimulation of the JAX reference.
//
// Round-12 post-mortem of R11: WRITE_SIZE=114MB/dispatch (state is 0.25MB)
// + VGPR=128 = massive scratch spill. The double-buffer staging regs held
// across a 64-deep unrolled chunk + sched_barrier(0) pins blew regalloc.
// The bit-pack MODEL survived (passed bit-exact; arithmetic sound).
// Round-12: same model, pressure-minimal implementation:
//  - W tile [256k][64c] = 64 KiB staged ONCE, single-buffered, 4-batch
//    prologue (4 transient float4) — no mid-loop staging, no sched_barrier
//  - masks in LDS (64x8 words = 2 KiB); 4 ds_read_b32 per 32-k group
//    (only 4 mask words live at a time)
//  - inner loop: 1 ds_read_b128 (W; 16 distinct 16B in a 256B span =
//    2-way + broadcast = free) + 4 bfe + 4 cvt + 16 fma per k.
//    Zero global loads, zero barriers, no pinning (R4-proven regime).
//  - model: VALU 10.2us + LDS 10.2us per phase, overlapping pipes (m114);
//    70 KiB LDS -> 2 blocks/CU; ~55 VGPR, launch_bounds(256,2).
// Accumulation order per output unchanged: ascending-k single-acc fma chain;
// s = (float)((word>>kk)&1) is bit-identical 1.0f/+0.0f to stored floats.
//
// ASSUMPTION STACK (verified bit-exact in earlier rounds):
//  A1: jax_threefry_partitionable = True:
//      split(key,n)[i] = TF(key,(0,i)); bits32[j] = TF0(key,(0,j)) ^ TF1(key,(0,j))
//  A2: logistic(x) = 1/(1+exp(-x)), IEEE fdiv
//  A3: exp = XLA-CPU vectorized Cephes/Eigen pexp
//  A4: dot = ascending-k single-accumulator fma chain (exact 0/1 products)
//  A5: x = (dot + udot) + bias association
//  Output dtype: int32 0/1 (harness reads d_out as int32).
// ============================================================================

#pragma clang fp contract(off)

#define BATCH 8192
#define NU 64
#define NF 256   // num_v == num_h == 256
#define BM 64    // rows per block in k_phase
#define BN 64    // cols per block in k_phase
#define RTI 16   // rows per block in k_init / k_udot
#define THERM 24
#define NSAMP 8

// ---------------- Threefry-2x32 (JAX rotation/injection schedule) ----------
__host__ __device__ __forceinline__ void tf2x32(uint32_t k0, uint32_t k1,
                                                uint32_t x0, uint32_t x1,
                                                uint32_t* o0, uint32_t* o1) {
  uint32_t ks2 = k0 ^ k1 ^ 0x1BD11BDAu;
  x0 += k0; x1 += k1;
#define TFR(r) { x0 += x1; x1 = (x1 << (r)) | (x1 >> (32 - (r))); x1 ^= x0; }
  TFR(13) TFR(15) TFR(26) TFR(6)
  x0 += k1;  x1 += ks2 + 1u;
  TFR(17) TFR(29) TFR(16) TFR(24)
  x0 += ks2; x1 += k0 + 2u;
  TFR(13) TFR(15) TFR(26) TFR(6)
  x0 += k0;  x1 += k1 + 3u;
  TFR(17) TFR(29) TFR(16) TFR(24)
  x0 += k1;  x1 += ks2 + 4u;
  TFR(13) TFR(15) TFR(26) TFR(6)
  x0 += ks2; x1 += k0 + 5u;
#undef TFR
  *o0 = x0; *o1 = x1;
}

// ---------------- XLA-CPU expf (Cephes/Eigen polynomial) -------------------
__device__ __forceinline__ float xla_expf(float x) {
  float xc = fminf(x, 88.3762626647950f);
  xc = fmaxf(xc, -88.3762626647949f);
  float fx = floorf(__builtin_fmaf(xc, 1.44269504088896341f, 0.5f));
  float tmp = 0.693359375f * fx;          // separate rounding (contract off)
  float z = -2.12194440e-4f * fx;
  float r = xc - tmp;
  r = r - z;
  z = r * r;
  float y = __builtin_fmaf(r, 1.9875691500e-4f, 1.3981999507e-3f);
  y = __builtin_fmaf(y, r, 8.3334519073e-3f);
  y = __builtin_fmaf(y, r, 4.1665795894e-2f);
  y = __builtin_fmaf(y, r, 1.6666665459e-1f);
  y = __builtin_fmaf(y, r, 5.0000001201e-1f);
  y = __builtin_fmaf(y, z, r);
  y = y + 1.0f;
  int n = (int)fx;
  float p2 = __int_as_float((n + 127) << 23);
  float res = y * p2;
  return fmaxf(res, x);                   // Eigen pexp: pmax(res, original x)
}

__device__ __forceinline__ float sigmoid_ref(float x) {
  float e = xla_expf(-x);                 // negate exact
  return 1.0f / (1.0f + e);               // IEEE fdiv (no fast-math)
}

// bern: partitionable threefry bits -> uniform [0,1) -> (u < p)
__device__ __forceinline__ float bern_sample(uint32_t key0, uint32_t key1,
                                             uint32_t idx, float p) {
  uint32_t b0, b1;
  tf2x32(key0, key1, 0u, idx, &b0, &b1);  // counter = (hi=0, lo=flat_idx)
  uint32_t bits = b0 ^ b1;                // 32-bit path XORs both words
  float u = __uint_as_float((bits >> 9) | 0x3f800000u) - 1.0f;
  return (u < p) ? 1.0f : 0.0f;
}

// ---------------- kernels ---------------------------------------------------
__global__ void k_transpose(const float* __restrict__ Whv,
                            float* __restrict__ WhvT) {
  int j = threadIdx.x;  // hidden
  int k = blockIdx.x;   // visible
  WhvT[k * NF + j] = Whv[j * NF + k];
}

// out[row][j] = sum_k u[row][k] * W[j][k], ascending k (exact products).
__global__ __launch_bounds__(256, 2) void k_udot(const float* __restrict__ U,
                                                 const float* __restrict__ W,
                                                 float* __restrict__ out) {
  __shared__ __align__(16) float Ulds[NU * RTI];  // [k][i], 4 KiB
  const int j = threadIdx.x;
  const int i0 = blockIdx.x * RTI;
  const int si = j & 15;
  const int sg = j >> 4;
  {
    float4 u4 = *(const float4*)(U + (size_t)(i0 + si) * NU + sg * 4);
    Ulds[(sg * 4 + 0) * RTI + si] = u4.x;
    Ulds[(sg * 4 + 1) * RTI + si] = u4.y;
    Ulds[(sg * 4 + 2) * RTI + si] = u4.z;
    Ulds[(sg * 4 + 3) * RTI + si] = u4.w;
  }
  float wreg[NU];
  const float4* wr4 = (const float4*)(W + (size_t)j * NU);
#pragma unroll
  for (int r = 0; r < NU / 4; ++r) {
    float4 t = wr4[r];
    wreg[4 * r + 0] = t.x; wreg[4 * r + 1] = t.y;
    wreg[4 * r + 2] = t.z; wreg[4 * r + 3] = t.w;
  }
  __syncthreads();
  float acc[RTI];
#pragma unroll
  for (int i = 0; i < RTI; ++i) acc[i] = 0.0f;
#pragma unroll
  for (int kk = 0; kk < NU; ++kk) {
    const float w = wreg[kk];
    const float4 s0 = *(const float4*)(&Ulds[kk * RTI + 0]);
    const float4 s1 = *(const float4*)(&Ulds[kk * RTI + 4]);
    const float4 s2 = *(const float4*)(&Ulds[kk * RTI + 8]);
    const float4 s3 = *(const float4*)(&Ulds[kk * RTI + 12]);
    acc[0]  = __builtin_fmaf(s0.x, w, acc[0]);
    acc[1]  = __builtin_fmaf(s0.y, w, acc[1]);
    acc[2]  = __builtin_fmaf(s0.z, w, acc[2]);
    acc[3]  = __builtin_fmaf(s0.w, w, acc[3]);
    acc[4]  = __builtin_fmaf(s1.x, w, acc[4]);
    acc[5]  = __builtin_fmaf(s1.y, w, acc[5]);
    acc[6]  = __builtin_fmaf(s1.z, w, acc[6]);
    acc[7]  = __builtin_fmaf(s1.w, w, acc[7]);
    acc[8]  = __builtin_fmaf(s2.x, w, acc[8]);
    acc[9]  = __builtin_fmaf(s2.y, w, acc[9]);
    acc[10] = __builtin_fmaf(s2.z, w, acc[10]);
    acc[11] = __builtin_fmaf(s2.w, w, acc[11]);
    acc[12] = __builtin_fmaf(s3.x, w, acc[12]);
    acc[13] = __builtin_fmaf(s3.y, w, acc[13]);
    acc[14] = __builtin_fmaf(s3.z, w, acc[14]);
    acc[15] = __builtin_fmaf(s3.w, w, acc[15]);
  }
#pragma unroll
  for (int i = 0; i < RTI; ++i)
    out[(size_t)(i0 + i) * NF + j] = acc[i];   // row-major (coalesced)
}

// v0 = bern(ks[0], sigmoid(uv + bv)); emits PACKED state bits via ballot.
__global__ __launch_bounds__(256) void k_init(const float* __restrict__ uv,
                                              const float* __restrict__ bv,
                                              uint32_t* __restrict__ Vb,
                                              uint32_t key0, uint32_t key1) {
  const int j = threadIdx.x;
  const int i0 = blockIdx.x * RTI;
  const int wv = j >> 6, lane = j & 63;
  const float b = bv[j];
#pragma unroll
  for (int i = 0; i < RTI; ++i) {
    const int row = i0 + i;
    const uint32_t idx = (uint32_t)(row * NF + j);
    const float p = sigmoid_ref(uv[idx] + b);
    const float v = bern_sample(key0, key1, idx, p);
    unsigned long long m = __ballot(v != 0.0f);   // bit l = col 64*wv + l
    if (lane == 0)
      *(uint2*)(Vb + (size_t)row * 8 + 2 * wv) =
          make_uint2((uint32_t)m, (uint32_t)(m >> 32));
  }
}

// One Gibbs half-step: Ob = bern(key, sigmoid((S @ W) + C + bias)), packed.
// Sb: prev state bits [8192][8 words]; W: [256 k][256 j] k-major;
// C: u-dot [8192][256]; Ob: next-state bits; smp: optional int32 samples.
// Block 64x64, thread 4x4. W tile [256][64] = 64 KiB staged once; masks in
// LDS (2 KiB). Inner loop: 1 ds_read_b128 + 4 bfe + 4 cvt + 16 fma per k.
__global__ __launch_bounds__(256, 2) void k_phase(
    const uint32_t* __restrict__ Sb, const float* __restrict__ W,
    const float* __restrict__ C, const float* __restrict__ bias,
    uint32_t* __restrict__ Ob, int* __restrict__ smp,
    uint32_t key0, uint32_t key1) {
  __shared__ __align__(16) float Wlds[NF * BN];     // 64 KiB [k][c]
  __shared__ __align__(8) uint32_t Smask[BM * 8];   // 2 KiB [row][word]
  __shared__ uint32_t Nib[BM * 16];                 // 4 KiB nibble scratch
  const int t  = threadIdx.x;
  const int i0 = (blockIdx.x & 127) * BM;   // 128 row-blocks (consecutive ids
  const int c0 = (blockIdx.x >> 7) * BN;    //   share the same W col-slice)
  const int rg = t >> 4, cg = t & 15;
  const int jc = c0 + cg * 4;               // thread's 4 cols
  const int r0 = i0 + rg * 4;               // thread's 4 rows

  // stage masks: 64 rows x 8 words; thread t -> row t>>2, words (t&3)*2..+1
  {
    const int row = t >> 2, wo = (t & 3) * 2;
    *(uint2*)(&Smask[row * 8 + wo]) =
        *(const uint2*)(Sb + (size_t)(i0 + row) * 8 + wo);
  }
  // stage W tile in 4 batches of 4 float4 (bounded register pressure)
#pragma unroll
  for (int b = 0; b < 4; ++b) {
    float4 tmp0, tmp1, tmp2, tmp3;
    {
      const int f0 = (b * 4 + 0) * 256 + t;
      const int f1 = (b * 4 + 1) * 256 + t;
      const int f2 = (b * 4 + 2) * 256 + t;
      const int f3 = (b * 4 + 3) * 256 + t;
      tmp0 = *(const float4*)(W + (size_t)(f0 >> 4) * NF + c0 + (f0 & 15) * 4);
      tmp1 = *(const float4*)(W + (size_t)(f1 >> 4) * NF + c0 + (f1 & 15) * 4);
      tmp2 = *(const float4*)(W + (size_t)(f2 >> 4) * NF + c0 + (f2 & 15) * 4);
      tmp3 = *(const float4*)(W + (size_t)(f3 >> 4) * NF + c0 + (f3 & 15) * 4);
      *(float4*)(&Wlds[(size_t)(f0 >> 4) * BN + (f0 & 15) * 4]) = tmp0;
      *(float4*)(&Wlds[(size_t)(f1 >> 4) * BN + (f1 & 15) * 4]) = tmp1;
      *(float4*)(&Wlds[(size_t)(f2 >> 4) * BN + (f2 & 15) * 4]) = tmp2;
      *(float4*)(&Wlds[(size_t)(f3 >> 4) * BN + (f3 & 15) * 4]) = tmp3;
    }
  }
  __syncthreads();

  float acc[16];                      // acc[ri*4+ci]
#pragma unroll
  for (int q = 0; q < 16; ++q) acc[q] = 0.0f;

  const uint32_t* smrow = &Smask[(rg * 4) * 8];

  for (int wi = 0; wi < 8; ++wi) {    // 8 mask words = 8 x 32 k, ascending
    const uint32_t wd0 = smrow[0 * 8 + wi];
    const uint32_t wd1 = smrow[1 * 8 + wi];
    const uint32_t wd2 = smrow[2 * 8 + wi];
    const uint32_t wd3 = smrow[3 * 8 + wi];
    const float* wl = &Wlds[(wi * 32) * BN + cg * 4];
#pragma unroll
    for (int kk = 0; kk < 32; ++kk) {
      const float4 w = *(const float4*)(wl + kk * BN);   // 2-way/bcast: free
      const float s0 = (float)((wd0 >> kk) & 1u);        // 1.0f / +0.0f
      const float s1 = (float)((wd1 >> kk) & 1u);
      const float s2 = (float)((wd2 >> kk) & 1u);
      const float s3 = (float)((wd3 >> kk) & 1u);
      acc[0]  = __builtin_fmaf(s0, w.x, acc[0]);   // exact products
      acc[1]  = __builtin_fmaf(s0, w.y, acc[1]);
      acc[2]  = __builtin_fmaf(s0, w.z, acc[2]);
      acc[3]  = __builtin_fmaf(s0, w.w, acc[3]);
      acc[4]  = __builtin_fmaf(s1, w.x, acc[4]);
      acc[5]  = __builtin_fmaf(s1, w.y, acc[5]);
      acc[6]  = __builtin_fmaf(s1, w.z, acc[6]);
      acc[7]  = __builtin_fmaf(s1, w.w, acc[7]);
      acc[8]  = __builtin_fmaf(s2, w.x, acc[8]);
      acc[9]  = __builtin_fmaf(s2, w.y, acc[9]);
      acc[10] = __builtin_fmaf(s2, w.z, acc[10]);
      acc[11] = __builtin_fmaf(s2, w.w, acc[11]);
      acc[12] = __builtin_fmaf(s3, w.x, acc[12]);
      acc[13] = __builtin_fmaf(s3, w.y, acc[13]);
      acc[14] = __builtin_fmaf(s3, w.z, acc[14]);
      acc[15] = __builtin_fmaf(s3, w.w, acc[15]);
    }
  }

  // epilogue: x = (dot + udot) + bias ; p = sigmoid ; bern
  const float4 b4 = *(const float4*)(bias + jc);
  float vals[16];
#pragma unroll
  for (int ri = 0; ri < 4; ++ri) {
    const int row = r0 + ri;
    const float4 c4 = *(const float4*)(C + (size_t)row * NF + jc);
    const uint32_t idx0 = (uint32_t)(row * NF + jc);
    vals[ri * 4 + 0] = bern_sample(key0, key1, idx0 + 0,
        sigmoid_ref((acc[ri * 4 + 0] + c4.x) + b4.x));
    vals[ri * 4 + 1] = bern_sample(key0, key1, idx0 + 1,
        sigmoid_ref((acc[ri * 4 + 1] + c4.y) + b4.y));
    vals[ri * 4 + 2] = bern_sample(key0, key1, idx0 + 2,
        sigmoid_ref((acc[ri * 4 + 2] + c4.z) + b4.z));
    vals[ri * 4 + 3] = bern_sample(key0, key1, idx0 + 3,
        sigmoid_ref((acc[ri * 4 + 3] + c4.w) + b4.w));
  }

  // int32 sample output (row-major)
  if (smp) {
#pragma unroll
    for (int ri = 0; ri < 4; ++ri) {
      const int row = r0 + ri;
      int4 o;
      o.x = (vals[ri * 4 + 0] != 0.0f) ? 1 : 0;
      o.y = (vals[ri * 4 + 1] != 0.0f) ? 1 : 0;
      o.z = (vals[ri * 4 + 2] != 0.0f) ? 1 : 0;
      o.w = (vals[ri * 4 + 3] != 0.0f) ? 1 : 0;
      *(int4*)(smp + (size_t)row * NF + jc) = o;
    }
  }

  // packed next-state: nibble per (row, cg) -> LDS -> word assembly
#pragma unroll
  for (int ri = 0; ri < 4; ++ri) {
    uint32_t nb = (vals[ri * 4 + 0] != 0.0f ? 1u : 0u) |
                  (vals[ri * 4 + 1] != 0.0f ? 2u : 0u) |
                  (vals[ri * 4 + 2] != 0.0f ? 4u : 0u) |
                  (vals[ri * 4 + 3] != 0.0f ? 8u : 0u);
    Nib[(rg * 4 + ri) * 16 + cg] = nb;
  }
  __syncthreads();
  if (t < 128) {                       // 2 words per row: 64 rows x 2
    const int row = t >> 1, half = t & 1;
    const uint32_t* nb = &Nib[row * 16 + half * 8];
    uint32_t wrd = nb[0] | (nb[1] << 4) | (nb[2] << 8) | (nb[3] << 12) |
                   (nb[4] << 16) | (nb[5] << 20) | (nb[6] << 24) | (nb[7] << 28);
    Ob[(size_t)(i0 + row) * 8 + (c0 >> 5) + half] = wrd;
  }
}

// ---------------- launch ----------------------------------------------------
extern "C" void kernel_launch(void* const* d_in, const int* in_sizes, int n_in,
                              void* d_out, int out_size, void* d_ws, size_t ws_size,
                              hipStream_t stream) {
  const float* u_state = (const float*)d_in[0];  // [8192][64] 0/1 floats
  const float* Wvu     = (const float*)d_in[1];  // [256][64]
  const float* Whu     = (const float*)d_in[2];  // [256][64]
  const float* Whv     = (const float*)d_in[3];  // [256][256]
  const float* bv      = (const float*)d_in[4];  // [256]
  const float* bh      = (const float*)d_in[5];  // [256]
  int* out = (int*)d_out;                        // [8][8192][256] as int32 0/1

  // workspace layout: WhvT 256KB, uh/uv 8MB each, Vb/Hb 256KB each (~17.3MB)
  float* ws   = (float*)d_ws;
  float* WhvT = ws;                          // 65536 f
  float* uh   = WhvT + NF * NF;              // [8192][256]
  float* uv   = uh + (size_t)BATCH * NF;
  uint32_t* Vb = (uint32_t*)(uv + (size_t)BATCH * NF);  // [8192][8]
  uint32_t* Hb = Vb + (size_t)BATCH * 8;                // [8192][8]

  // ---- host-side key schedule (pure CPU, deterministic) ----
  uint32_t s0[THERM + NSAMP + 1], s1[THERM + NSAMP + 1];
  for (uint32_t i = 0; i < THERM + NSAMP + 1; ++i)
    tf2x32(0u, 1u, 0u, i, &s0[i], &s1[i]);

  k_transpose<<<NF, NF, 0, stream>>>(Whv, WhvT);
  k_udot<<<BATCH / RTI, NF, 0, stream>>>(u_state, Whu, uh);   // u @ Whu.T
  k_udot<<<BATCH / RTI, NF, 0, stream>>>(u_state, Wvu, uv);   // u @ Wvu.T
  k_init<<<BATCH / RTI, NF, 0, stream>>>(uv, bv, Vb, s0[0], s1[0]);

  const int phase_blocks = (BATCH / BM) * (NF / BN);   // 128 * 4 = 512
  for (int t = 0; t < THERM + NSAMP; ++t) {
    uint32_t kh0, kh1, kv0, kv1;
    tf2x32(s0[1 + t], s1[1 + t], 0u, 0u, &kh0, &kh1);
    tf2x32(s0[1 + t], s1[1 + t], 0u, 1u, &kv0, &kv1);
    int* smp = (t >= THERM) ? out + (size_t)(t - THERM) * BATCH * NF : (int*)nullptr;
    // h = bern(k1, sigmoid(v @ Whv.T + uh + bh))
    k_phase<<<phase_blocks, NF, 0, stream>>>(Vb, WhvT, uh, bh, Hb, (int*)nullptr, kh0, kh1);
    // v = bern(k2, sigmoid(h @ Whv + uv + bv)) ; emit sample when t>=THERM
    k_phase<<<phase_blocks, NF, 0, stream>>>(Hb, Whv, uv, bv, Vb, smp, kv0, kv1);
  }
  (void)in_sizes; (void)n_in; (void)out_size; (void)ws_size;
}